// Round 5
// baseline (115.471 us; speedup 1.0000x reference)
//
#include <hip/hip_runtime.h>
#include <math.h>

#define B 32
#define C 8
#define T 512
#define NSH 5
#define NCLS 10
#define NFEAT 160   // 4 groups * 5 * 8

// d_out layout (f32): out[320] | dists[5120] | probs[5120] | loss[1]
#define OUT_OFF    0
#define DIST_OFF   (B * NCLS)                 // 320
#define PROB_OFF   (DIST_OFF + B * NFEAT)     // 5440
#define LOSS_OFF   (PROB_OFF + B * NFEAT)     // 10560

// d_ws (f32): [0..639] div pair partials | [640..643] |Wout| partials
//             [648..1159] (ns, nb) per bc row (256 x 2)
#define MUINV_OFF 648

// ---------------------------------------------------------------------------
// prep: per-row normalization constants + loss partials
// ---------------------------------------------------------------------------
__global__ __launch_bounds__(256) void prep_kernel(
    const float* __restrict__ x,
    const float* __restrict__ w0, const float* __restrict__ w1,
    const float* __restrict__ w2, const float* __restrict__ w3,
    const float* __restrict__ Wout,
    float* __restrict__ wsf)
{
    const int blk  = blockIdx.x;
    const int wv   = __builtin_amdgcn_readfirstlane(threadIdx.x >> 6);
    const int lane = threadIdx.x & 63;

    if (blk < 64) {
        const int bc = blk * 4 + wv;
        const float* xr = x + bc * T;
        const float4 u0 = *(const float4*)(xr + lane * 4);
        const float4 u1 = *(const float4*)(xr + 256 + lane * 4);
        float s = u0.x + u0.y + u0.z + u0.w + u1.x + u1.y + u1.z + u1.w;
        #pragma unroll
        for (int off = 32; off; off >>= 1) s += __shfl_down(s, off);
        const float mu = __shfl(s, 0) * (1.0f / T);
        float sq = (u0.x-mu)*(u0.x-mu) + (u0.y-mu)*(u0.y-mu) + (u0.z-mu)*(u0.z-mu) + (u0.w-mu)*(u0.w-mu)
                 + (u1.x-mu)*(u1.x-mu) + (u1.y-mu)*(u1.y-mu) + (u1.z-mu)*(u1.z-mu) + (u1.w-mu)*(u1.w-mu);
        #pragma unroll
        for (int off = 32; off; off >>= 1) sq += __shfl_down(sq, off);
        if (lane == 0) {
            const float var = sq * (1.0f / (T - 1));
            const float ns  = 1.0f / (sqrtf(var) + 1e-8f);
            wsf[MUINV_OFF + 2*bc]     = ns;
            wsf[MUINV_OFF + 2*bc + 1] = -mu * ns;
        }
    } else if (blk < 224) {
        // diversity pair partials: one ordered pair per wave
        const int task = (blk - 64) * 4 + wv;   // 0..639
        const int g  = task / 160;
        const int r  = task - g * 160;
        const int c  = r / 20;
        const int pr = r - c * 20;
        const int i  = pr >> 2;
        const int j0 = pr & 3;
        const int j  = j0 + (j0 >= i ? 1 : 0);
        const float* wptrs[4] = { w0, w1, w2, w3 };
        const int    Ls[4]    = { 52, 103, 154, 256 };
        const int L = Ls[g];
        const float* wi = wptrs[g] + (i * C + c) * L;
        const float* wj = wptrs[g] + (j * C + c) * L;
        float ss = 0.0f;
        for (int t2 = lane; t2 < L; t2 += 64) {
            const float df = wj[t2] - wi[t2] + 1e-6f;
            ss += df * df;
        }
        #pragma unroll
        for (int off = 32; off; off >>= 1) ss += __shfl_down(ss, off);
        if (lane == 0) wsf[task] = expf(-sqrtf(ss));
    } else {
        // |Wout| partials: wave wv sums elements [wv*400, wv*400+400)
        float rg = 0.0f;
        #pragma unroll
        for (int k2 = 0; k2 < 7; ++k2) {
            const int e = lane + k2 * 64;
            if (e < 400) rg += fabsf(Wout[wv * 400 + e]);
        }
        #pragma unroll
        for (int off = 32; off; off >>= 1) rg += __shfl_down(rg, off);
        if (lane == 0) wsf[640 + wv] = rg;
    }
}

// ---------------------------------------------------------------------------
// shapelet: one wave per (bc, g, n) task.
//   MPL  = m-windows per lane = ceil(M/64)  (idle lanes are free; instr ~ L*MPL)
//   CW   = valid window span at phase start (>= MPL+3)
//   ALIGN= x-chunk load width (4/2/1), chosen so lane*MPL keeps alignment
// 16-reg circular x-window, 4-deep chunk prefetch (pv0..pv3), w values
// double-buffered 16-ahead in wave-uniform regs (s_load pipelining).
// ---------------------------------------------------------------------------
template<int L, int M, int GOFF, int MPL, int CW, int ALIGN>
__device__ __forceinline__ void shapelet_task(
    const float* __restrict__ xrow,
    const float* __restrict__ wrow,
    const float* __restrict__ pmrow,
    const float* __restrict__ minv2,
    float* __restrict__ out, int b, int c, int n)
{
    const int lane  = threadIdx.x & 63;
    const int sbase = lane * MPL;
    const int sb = (sbase < M) ? sbase : 0;

    const float ns = minv2[0];
    const float nb = minv2[1];

    float U[16];
    float acc[MPL];
    #pragma unroll
    for (int k = 0; k < MPL; ++k) acc[k] = 0.0f;

    auto LOADCHUNK = [&](int addr) -> float4 {
        int a = addr > (T - 4) ? (T - 4) : addr;
        if constexpr (ALIGN == 4) {
            return *(const float4*)(xrow + a);
        } else if constexpr (ALIGN == 2) {
            const float2 lo = *(const float2*)(xrow + a);
            const float2 hi = *(const float2*)(xrow + a + 2);
            return float4{lo.x, lo.y, hi.x, hi.y};
        } else {
            return float4{xrow[a], xrow[a+1], xrow[a+2], xrow[a+3]};
        }
    };

    // initial window fill: positions [0 .. CW-1]
    if constexpr (ALIGN == 4) {
        #pragma unroll
        for (int q = 0; q < CW / 4; ++q) {
            const float4 v = *(const float4*)(xrow + sb + q * 4);
            U[q*4+0] = fmaf(v.x, ns, nb); U[q*4+1] = fmaf(v.y, ns, nb);
            U[q*4+2] = fmaf(v.z, ns, nb); U[q*4+3] = fmaf(v.w, ns, nb);
        }
    } else if constexpr (ALIGN == 2) {
        #pragma unroll
        for (int q = 0; q < CW / 2; ++q) {
            const float2 v = *(const float2*)(xrow + sb + q * 2);
            U[q*2+0] = fmaf(v.x, ns, nb); U[q*2+1] = fmaf(v.y, ns, nb);
        }
    } else {
        #pragma unroll
        for (int q = 0; q < CW; ++q)
            U[q] = fmaf(xrow[sb + q], ns, nb);
    }

    // 4-deep chunk prefetch
    float4 pv0 = LOADCHUNK(sb + CW);
    float4 pv1 = LOADCHUNK(sb + CW + 4);
    float4 pv2 = LOADCHUNK(sb + CW + 8);
    float4 pv3 = LOADCHUNK(sb + CW + 12);

    // w double-buffer (wave-uniform -> SGPR)
    float wc[16];
    #pragma unroll
    for (int q = 0; q < 16; ++q) wc[q] = wrow[q];   // L >= 52 > 16

    int j = 0;

#define PHASE(BB, PV, WB)                                                  \
    {                                                                      \
        U[(BB + CW + 0) & 15] = fmaf(PV.x, ns, nb);                        \
        U[(BB + CW + 1) & 15] = fmaf(PV.y, ns, nb);                        \
        U[(BB + CW + 2) & 15] = fmaf(PV.z, ns, nb);                        \
        U[(BB + CW + 3) & 15] = fmaf(PV.w, ns, nb);                        \
        PV = LOADCHUNK(sb + j + CW + 16);                                  \
        _Pragma("unroll")                                                  \
        for (int jj = 0; jj < 4; ++jj) {                                   \
            const float wj = wc[WB + jj];                                  \
            _Pragma("unroll")                                              \
            for (int k = 0; k < MPL; ++k)                                  \
                acc[k] += fabsf(U[(BB + jj + k) & 15] - wj);               \
        }                                                                  \
        j += 4;                                                            \
    }

    constexpr int NP    = L / 4;     // full 4-j phases
    constexpr int NLOOP = NP / 4;
    constexpr int NTAIL = NP % 4;

    for (int it = 0; it < NLOOP; ++it) {
        // prefetch next 16 w values (consumed next iteration / tail)
        float nw[16];
        #pragma unroll
        for (int q = 0; q < 16; ++q) {
            int idx = j + 16 + q;
            idx = (idx < L) ? idx : (L - 1);
            nw[q] = wrow[idx];
        }
        PHASE(0,  pv0, 0)
        PHASE(4,  pv1, 4)
        PHASE(8,  pv2, 8)
        PHASE(12, pv3, 12)
        #pragma unroll
        for (int q = 0; q < 16; ++q) wc[q] = nw[q];
    }
    if constexpr (NTAIL >= 1) PHASE(0, pv0, 0)
    if constexpr (NTAIL >= 2) PHASE(4, pv1, 4)
    if constexpr (NTAIL >= 3) PHASE(8, pv2, 8)
#undef PHASE

    if constexpr ((L & 3) != 0) {        // scalar tail, window still valid
        constexpr int TB = (4 * NP) & 15;
        #pragma unroll
        for (int jt = 0; jt < (L & 3); ++jt) {
            const float wj = wc[NTAIL * 4 + jt];
            #pragma unroll
            for (int k = 0; k < MPL; ++k)
                acc[k] += fabsf(U[(TB + jt + k) & 15] - wj);
        }
    }

    constexpr float invL = 1.0f / (float)L;
    float mind = INFINITY, mind2 = INFINITY;
    #pragma unroll
    for (int k = 0; k < MPL; ++k) {
        const int m = sbase + k;
        if (m < M) {
            const float d = acc[k] * invL * pmrow[m];
            mind  = fminf(mind, d);
            mind2 = fminf(mind2, d * d);
        }
    }
    #pragma unroll
    for (int off = 32; off; off >>= 1) {
        mind  = fminf(mind,  __shfl_down(mind,  off));
        mind2 = fminf(mind2, __shfl_down(mind2, off));
    }
    if (lane == 0) {
        const int col = GOFF + n * C + c;
        out[DIST_OFF + b * NFEAT + col] = mind;
        out[PROB_OFF + b * NFEAT + col] = expf(-mind2);
    }
}

__global__ __launch_bounds__(256) void shapelet_kernel(
    const float* __restrict__ x,
    const float* __restrict__ w0, const float* __restrict__ w1,
    const float* __restrict__ w2, const float* __restrict__ w3,
    const float* __restrict__ p0, const float* __restrict__ p1,
    const float* __restrict__ p2, const float* __restrict__ p3,
    float* __restrict__ out, const float* __restrict__ wsf)
{
    const int blk = blockIdx.x;
    const int wv  = __builtin_amdgcn_readfirstlane(threadIdx.x >> 6);

    // longest group (g3) dispatches first for makespan
    int gsel, base;
    if      (blk < 320) { gsel = 3; base = 0;   }
    else if (blk < 640) { gsel = 2; base = 320; }
    else if (blk < 960) { gsel = 1; base = 640; }
    else                { gsel = 0; base = 960; }

    const int lt = (blk - base) * 4 + wv;   // 0..1279
    const int bc = lt / 5;
    const int n  = lt - bc * 5;
    const int c  = bc & 7;
    const int b  = bc >> 3;
    const float* xr = x + bc * T;
    const float* mi = wsf + MUINV_OFF + 2 * bc;

    switch (gsel) {
        case 3:  shapelet_task<256, 257, 120, 5,  8, 1>(xr, w3 + (n*C+c)*256, p3 + c*257, mi, out, b, c, n); break;
        case 2:  shapelet_task<154, 359,  80, 6, 10, 2>(xr, w2 + (n*C+c)*154, p2 + c*359, mi, out, b, c, n); break;
        case 1:  shapelet_task<103, 410,  40, 7, 12, 1>(xr, w1 + (n*C+c)*103, p1 + c*410, mi, out, b, c, n); break;
        default: shapelet_task< 52, 461,   0, 8, 12, 4>(xr, w0 + (n*C+c)*52,  p0 + c*461, mi, out, b, c, n); break;
    }
}

// ---------------------------------------------------------------------------
// head: GEMV + loss finalize
// ---------------------------------------------------------------------------
__global__ __launch_bounds__(64) void head_kernel(
    const float* __restrict__ Wout,
    const float* __restrict__ wsf,
    float* __restrict__ out)
{
    const int blk  = blockIdx.x;
    const int lane = threadIdx.x;
    if (blk < B * NCLS) {
        const int b = blk / NCLS, k = blk - b * NCLS;
        const float* pr = out + PROB_OFF + b * NFEAT;
        const float* wr = Wout + k * NFEAT;
        float acc = 0.0f;
        #pragma unroll
        for (int r = 0; r < 3; ++r) {
            const int f = lane + r * 64;
            if (f < NFEAT) acc += pr[f] * wr[f];
        }
        #pragma unroll
        for (int off = 32; off; off >>= 1) acc += __shfl_down(acc, off);
        if (lane == 0) out[OUT_OFF + blk] = acc;
    } else {
        float dv = 0.0f, rg = 0.0f;
        #pragma unroll
        for (int r = 0; r < 10; ++r) {
            const int i = lane + r * 64;
            if (i < 640) dv += wsf[i];
        }
        if (lane < 4) rg = wsf[640 + lane];
        #pragma unroll
        for (int off = 32; off; off >>= 1) {
            dv += __shfl_down(dv, off);
            rg += __shfl_down(rg, off);
        }
        if (lane == 0)
            out[LOSS_OFF] = 0.1f * (rg * (1.0f / 1600.0f)) + 0.1f * (dv * (1.0f / 200.0f));
    }
}

extern "C" void kernel_launch(void* const* d_in, const int* in_sizes, int n_in,
                              void* d_out, int out_size, void* d_ws, size_t ws_size,
                              hipStream_t stream) {
    // setup_inputs() dict order: x, w0, pcm0, w1, pcm1, w2, pcm2, w3, pcm3, W_out
    const float* x    = (const float*)d_in[0];
    const float* w0   = (const float*)d_in[1];
    const float* pcm0 = (const float*)d_in[2];
    const float* w1   = (const float*)d_in[3];
    const float* pcm1 = (const float*)d_in[4];
    const float* w2   = (const float*)d_in[5];
    const float* pcm2 = (const float*)d_in[6];
    const float* w3   = (const float*)d_in[7];
    const float* pcm3 = (const float*)d_in[8];
    const float* Wout = (const float*)d_in[9];
    float* out = (float*)d_out;
    float* wsf = (float*)d_ws;

    prep_kernel<<<225, 256, 0, stream>>>(x, w0, w1, w2, w3, Wout, wsf);
    shapelet_kernel<<<1280, 256, 0, stream>>>(
        x, w0, w1, w2, w3, pcm0, pcm1, pcm2, pcm3, out, wsf);
    head_kernel<<<B * NCLS + 1, 64, 0, stream>>>(Wout, wsf, out);
}

// Round 6
// 102.460 us; speedup vs baseline: 1.1270x; 1.1270x over previous
//
#include <hip/hip_runtime.h>
#include <math.h>

#define B 32
#define C 8
#define T 512
#define NSH 5
#define NCLS 10
#define NFEAT 160   // 4 groups * 5 * 8

// d_out layout (f32): out[320] | dists[5120] | probs[5120] | loss[1]
#define OUT_OFF    0
#define DIST_OFF   (B * NCLS)                 // 320
#define PROB_OFF   (DIST_OFF + B * NFEAT)     // 5440
#define LOSS_OFF   (PROB_OFF + B * NFEAT)     // 10560

// d_ws (f32): [0..639] div pair partials | [640..643] |Wout| partials
//             [1024 .. 1024+131071] normalized x (256 rows x 512)
#define XN_OFF 1024

// ---------------------------------------------------------------------------
// prep: normalize x rows into ws + loss partials
// ---------------------------------------------------------------------------
__global__ __launch_bounds__(256) void prep_kernel(
    const float* __restrict__ x,
    const float* __restrict__ w0, const float* __restrict__ w1,
    const float* __restrict__ w2, const float* __restrict__ w3,
    const float* __restrict__ Wout,
    float* __restrict__ wsf)
{
    const int blk  = blockIdx.x;
    const int wv   = __builtin_amdgcn_readfirstlane(threadIdx.x >> 6);
    const int lane = threadIdx.x & 63;

    if (blk < 64) {
        const int bc = blk * 4 + wv;
        const float* xr = x + bc * T;
        const float4 u0 = *(const float4*)(xr + lane * 4);
        const float4 u1 = *(const float4*)(xr + 256 + lane * 4);
        float s = u0.x + u0.y + u0.z + u0.w + u1.x + u1.y + u1.z + u1.w;
        #pragma unroll
        for (int off = 32; off; off >>= 1) s += __shfl_down(s, off);
        const float mu = __shfl(s, 0) * (1.0f / T);
        float sq = (u0.x-mu)*(u0.x-mu) + (u0.y-mu)*(u0.y-mu) + (u0.z-mu)*(u0.z-mu) + (u0.w-mu)*(u0.w-mu)
                 + (u1.x-mu)*(u1.x-mu) + (u1.y-mu)*(u1.y-mu) + (u1.z-mu)*(u1.z-mu) + (u1.w-mu)*(u1.w-mu);
        #pragma unroll
        for (int off = 32; off; off >>= 1) sq += __shfl_down(sq, off);
        const float var = __shfl(sq, 0) * (1.0f / (T - 1));
        const float ns  = 1.0f / (sqrtf(var) + 1e-8f);
        const float nbv = -mu * ns;
        float* xo = wsf + XN_OFF + bc * T;
        const float4 o0 = { fmaf(u0.x,ns,nbv), fmaf(u0.y,ns,nbv), fmaf(u0.z,ns,nbv), fmaf(u0.w,ns,nbv) };
        const float4 o1 = { fmaf(u1.x,ns,nbv), fmaf(u1.y,ns,nbv), fmaf(u1.z,ns,nbv), fmaf(u1.w,ns,nbv) };
        *(float4*)(xo + lane * 4)       = o0;
        *(float4*)(xo + 256 + lane * 4) = o1;
    } else if (blk < 224) {
        // diversity pair partials: one ordered pair per wave
        const int task = (blk - 64) * 4 + wv;   // 0..639
        const int g  = task / 160;
        const int r  = task - g * 160;
        const int c  = r / 20;
        const int pr = r - c * 20;
        const int i  = pr >> 2;
        const int j0 = pr & 3;
        const int j  = j0 + (j0 >= i ? 1 : 0);
        const float* wptrs[4] = { w0, w1, w2, w3 };
        const int    Ls[4]    = { 52, 103, 154, 256 };
        const int L = Ls[g];
        const float* wi = wptrs[g] + (i * C + c) * L;
        const float* wj = wptrs[g] + (j * C + c) * L;
        float ss = 0.0f;
        for (int t2 = lane; t2 < L; t2 += 64) {
            const float df = wj[t2] - wi[t2] + 1e-6f;
            ss += df * df;
        }
        #pragma unroll
        for (int off = 32; off; off >>= 1) ss += __shfl_down(ss, off);
        if (lane == 0) wsf[task] = expf(-sqrtf(ss));
    } else {
        // |Wout| partials
        float rg = 0.0f;
        #pragma unroll
        for (int k2 = 0; k2 < 7; ++k2) {
            const int e = lane + k2 * 64;
            if (e < 400) rg += fabsf(Wout[wv * 400 + e]);
        }
        #pragma unroll
        for (int off = 32; off; off >>= 1) rg += __shfl_down(rg, off);
        if (lane == 0) wsf[640 + wv] = rg;
    }
}

// ---------------------------------------------------------------------------
// shapelet: one wave per (bc, m-slice of 64). MPL=1: lane owns ONE window m,
// all 5 shapelets (n) computed together. x loads are lane-contiguous
// (4-5 cache lines per load vs 20-32 before). w reads are wave-uniform
// (scalar/SMEM pipe, no TA pressure). x pre-normalized in ws by prep.
// ---------------------------------------------------------------------------
template<int L, int M, int S, int GOFF>
__device__ __forceinline__ void shapelet_task(
    const float* __restrict__ xn,    // ws + XN_OFF
    const float* __restrict__ wg,    // group w base (n,c,l)
    const float* __restrict__ pmg,   // group pcm base (c,m)
    float* __restrict__ out, int r)  // r in [0, 256*S)
{
    constexpr int CL = C * L;
    const int lane = threadIdx.x & 63;
    const int bc = r / S;            // uniform
    const int ms = r - bc * S;
    const int b  = bc >> 3, c = bc & 7;
    const int m  = ms * 64 + lane;
    const bool act = (m < M);
    const int mm = act ? m : 0;
    const float* xr = xn + bc * T + mm;   // per-lane, lane-contiguous
    const float* wr = wg + c * L;         // rows at stride CL for n=1..4

    float a0 = 0, a1 = 0, a2 = 0, a3 = 0, a4 = 0;

    // 8-deep x prefetch ring
    float xf[8];
    #pragma unroll
    for (int q = 0; q < 8; ++q) xf[q] = xr[q];

    constexpr int NB  = L / 8;
    constexpr int REM = L % 8;
    int j = 0;
    for (int it = 0; it < NB; ++it) {
        float nxf[8];
        #pragma unroll
        for (int q = 0; q < 8; ++q) {
            int o = j + 8 + q;
            o = (o < L) ? o : (L - 1);      // clamp keeps reads in-row
            nxf[q] = xr[o];
        }
        #pragma unroll
        for (int jj = 0; jj < 8; ++jj) {
            const float xv = xf[jj];
            const int jo = j + jj;
            a0 += fabsf(xv - wr[jo]);
            a1 += fabsf(xv - wr[CL + jo]);
            a2 += fabsf(xv - wr[2 * CL + jo]);
            a3 += fabsf(xv - wr[3 * CL + jo]);
            a4 += fabsf(xv - wr[4 * CL + jo]);
        }
        #pragma unroll
        for (int q = 0; q < 8; ++q) xf[q] = nxf[q];
        j += 8;
    }
    if constexpr (REM > 0) {
        #pragma unroll
        for (int jj = 0; jj < REM; ++jj) {
            const float xv = xf[jj];
            const int jo = NB * 8 + jj;
            a0 += fabsf(xv - wr[jo]);
            a1 += fabsf(xv - wr[CL + jo]);
            a2 += fabsf(xv - wr[2 * CL + jo]);
            a3 += fabsf(xv - wr[3 * CL + jo]);
            a4 += fabsf(xv - wr[4 * CL + jo]);
        }
    }

    const float pmv = pmg[c * M + mm];
    constexpr float invL = 1.0f / (float)L;
    const float scale = invL * pmv;

    float dv[5], d2[5];
    dv[0] = act ? a0 * scale : INFINITY;
    dv[1] = act ? a1 * scale : INFINITY;
    dv[2] = act ? a2 * scale : INFINITY;
    dv[3] = act ? a3 * scale : INFINITY;
    dv[4] = act ? a4 * scale : INFINITY;
    #pragma unroll
    for (int n = 0; n < 5; ++n) d2[n] = dv[n] * dv[n];

    #pragma unroll
    for (int off = 32; off; off >>= 1) {
        #pragma unroll
        for (int n = 0; n < 5; ++n) {
            dv[n] = fminf(dv[n], __shfl_down(dv[n], off));
            d2[n] = fminf(d2[n], __shfl_down(d2[n], off));
        }
    }
    if (lane == 0) {
        #pragma unroll
        for (int n = 0; n < 5; ++n) {
            const int col = GOFF + n * C + c;
            // slice-partial min -> combine across slices via atomic-free:
            // each slice writes its own min candidate with atomicMin? No:
            // slices are independent m-ranges; final min needs cross-slice
            // combine. Use global atomic-free two-step: write per-slice then
            // head combines? Simpler: atomic min via CAS is costly; instead
            // each slice writes to a per-slice scratch and head reduces.
            out[DIST_OFF + b * NFEAT + col] = dv[n];   // placeholder, fixed below
            out[PROB_OFF + b * NFEAT + col] = expf(-d2[n]);
        }
    }
}

// NOTE: the template above writes per-slice results; slices of the same
// (bc,g,n) would collide. Instead we route per-slice partials through ws and
// reduce in head. To keep one code path, the actual instantiation below
// writes to the partial buffer; see PART_OFF.
#define PART_OFF 200000   // ws float offset: per-wave partials [wt*2 + {0,1}] packed per (g,task)

template<int L, int M, int S, int GOFF>
__device__ __forceinline__ void shapelet_task_p(
    const float* __restrict__ xn,
    const float* __restrict__ wg,
    const float* __restrict__ pmg,
    float* __restrict__ wsf, int r, int pbase)
{
    constexpr int CL = C * L;
    const int lane = threadIdx.x & 63;
    const int bc = r / S;
    const int ms = r - bc * S;
    const int c  = bc & 7;
    const int m  = ms * 64 + lane;
    const bool act = (m < M);
    const int mm = act ? m : 0;
    const float* xr = xn + bc * T + mm;
    const float* wr = wg + c * L;

    float a0 = 0, a1 = 0, a2 = 0, a3 = 0, a4 = 0;
    float xf[8];
    #pragma unroll
    for (int q = 0; q < 8; ++q) xf[q] = xr[q];

    constexpr int NB  = L / 8;
    constexpr int REM = L % 8;
    int j = 0;
    for (int it = 0; it < NB; ++it) {
        float nxf[8];
        #pragma unroll
        for (int q = 0; q < 8; ++q) {
            int o = j + 8 + q;
            o = (o < L) ? o : (L - 1);
            nxf[q] = xr[o];
        }
        #pragma unroll
        for (int jj = 0; jj < 8; ++jj) {
            const float xv = xf[jj];
            const int jo = j + jj;
            a0 += fabsf(xv - wr[jo]);
            a1 += fabsf(xv - wr[CL + jo]);
            a2 += fabsf(xv - wr[2 * CL + jo]);
            a3 += fabsf(xv - wr[3 * CL + jo]);
            a4 += fabsf(xv - wr[4 * CL + jo]);
        }
        #pragma unroll
        for (int q = 0; q < 8; ++q) xf[q] = nxf[q];
        j += 8;
    }
    if constexpr (REM > 0) {
        #pragma unroll
        for (int jj = 0; jj < REM; ++jj) {
            const float xv = xf[jj];
            const int jo = NB * 8 + jj;
            a0 += fabsf(xv - wr[jo]);
            a1 += fabsf(xv - wr[CL + jo]);
            a2 += fabsf(xv - wr[2 * CL + jo]);
            a3 += fabsf(xv - wr[3 * CL + jo]);
            a4 += fabsf(xv - wr[4 * CL + jo]);
        }
    }

    const float pmv = pmg[c * M + mm];
    constexpr float invL = 1.0f / (float)L;
    const float scale = invL * pmv;

    float dv[5];
    dv[0] = act ? a0 * scale : INFINITY;
    dv[1] = act ? a1 * scale : INFINITY;
    dv[2] = act ? a2 * scale : INFINITY;
    dv[3] = act ? a3 * scale : INFINITY;
    dv[4] = act ? a4 * scale : INFINITY;
    float d2[5];
    #pragma unroll
    for (int n = 0; n < 5; ++n) d2[n] = act ? dv[n] * dv[n] : INFINITY;

    #pragma unroll
    for (int off = 32; off; off >>= 1) {
        #pragma unroll
        for (int n = 0; n < 5; ++n) {
            dv[n] = fminf(dv[n], __shfl_down(dv[n], off));
            d2[n] = fminf(d2[n], __shfl_down(d2[n], off));
        }
    }
    if (lane == 0) {
        // partial slot: [pbase + (r*5 + n)*2 + {0,1}] but r already encodes
        // (bc, slice); reducer needs slices of same (bc,n) adjacent:
        // layout: pbase + ((bc*5 + n)*S + ms)*2
        #pragma unroll
        for (int n = 0; n < 5; ++n) {
            float* p = wsf + pbase + ((bc * 5 + n) * S + ms) * 2;
            p[0] = dv[n];
            p[1] = d2[n];
        }
    }
}

__global__ __launch_bounds__(256, 7) void shapelet_kernel(
    const float* __restrict__ w0, const float* __restrict__ w1,
    const float* __restrict__ w2, const float* __restrict__ w3,
    const float* __restrict__ p0, const float* __restrict__ p1,
    const float* __restrict__ p2, const float* __restrict__ p3,
    float* __restrict__ wsf)
{
    const int wv = __builtin_amdgcn_readfirstlane(threadIdx.x >> 6);
    const int wt = blockIdx.x * 4 + wv;
    const float* xn = wsf + XN_OFF;

    // partial regions (floats): g3: 256*5*5*2=12800 | g2: *6*2=15360
    //                           g1: *7*2=17920 | g0: *8*2=20480
    // bases: g3 @ PART_OFF, g2 @ +12800, g1 @ +28160, g0 @ +46080
    if (wt < 1280)
        shapelet_task_p<256, 257, 5, 120>(xn, w3, p3, wsf, wt,          PART_OFF);
    else if (wt < 2816)
        shapelet_task_p<154, 359, 6,  80>(xn, w2, p2, wsf, wt - 1280,   PART_OFF + 12800);
    else if (wt < 4608)
        shapelet_task_p<103, 410, 7,  40>(xn, w1, p1, wsf, wt - 2816,   PART_OFF + 28160);
    else
        shapelet_task_p< 52, 461, 8,   0>(xn, w0, p0, wsf, wt - 4608,   PART_OFF + 46080);
}

// ---------------------------------------------------------------------------
// finalize: reduce slice partials -> dists/probs, then GEMV + loss
// one wave per (bc, g): reduces 5n x S slices   => 1024 waves = 256 blocks
// ---------------------------------------------------------------------------
__global__ __launch_bounds__(256) void reduce_kernel(
    const float* __restrict__ wsf, float* __restrict__ out)
{
    const int wv   = __builtin_amdgcn_readfirstlane(threadIdx.x >> 6);
    const int lane = threadIdx.x & 63;
    const int t    = blockIdx.x * 4 + wv;    // 0..1023 = bc*4 + g
    const int bc = t >> 2, g = t & 3;
    const int b = bc >> 3, c = bc & 7;

    int S, pbase, goff;
    switch (g) {
        case 3:  S = 5; pbase = PART_OFF;          goff = 120; break;
        case 2:  S = 6; pbase = PART_OFF + 12800;  goff = 80;  break;
        case 1:  S = 7; pbase = PART_OFF + 28160;  goff = 40;  break;
        default: S = 8; pbase = PART_OFF + 46080;  goff = 0;   break;
    }
    // elements for this bc: 5n * S slices * 2 <= 80; lane e covers one float
    const int tot = 5 * S * 2;
    // lane -> (n, ms, which): layout ((bc*5+n)*S+ms)*2+q
    float v = INFINITY;
    if (lane < tot) v = wsf[pbase + (bc * 5) * S * 2 + lane];
    // min across the S slices for fixed (n, q): elements with same
    // (lane % 2, lane / (S*2)) group; do it serially per lane0 instead:
    // simpler: shuffle-gather per (n,q) by lane responsibility:
    // lanes 0..9 own (n = lane/2, q = lane&1): min over ms of
    // wsf[... (n*S + ms)*2 + q]
    if (lane < 10) {
        const int n = lane >> 1, q = lane & 1;
        const float* p = wsf + pbase + ((bc * 5 + n) * S) * 2 + q;
        float mn = INFINITY;
        for (int msi = 0; msi < S; ++msi) mn = fminf(mn, p[msi * 2]);
        const int col = goff + n * C + c;
        if (q == 0) out[DIST_OFF + b * NFEAT + col] = mn;
        else        out[PROB_OFF + b * NFEAT + col] = expf(-mn);
    }
}

__global__ __launch_bounds__(64) void head_kernel(
    const float* __restrict__ Wout,
    const float* __restrict__ wsf,
    float* __restrict__ out)
{
    const int blk  = blockIdx.x;
    const int lane = threadIdx.x;
    if (blk < B * NCLS) {
        const int b = blk / NCLS, k = blk - b * NCLS;
        const float* pr = out + PROB_OFF + b * NFEAT;
        const float* wr = Wout + k * NFEAT;
        float acc = 0.0f;
        #pragma unroll
        for (int r = 0; r < 3; ++r) {
            const int f = lane + r * 64;
            if (f < NFEAT) acc += pr[f] * wr[f];
        }
        #pragma unroll
        for (int off = 32; off; off >>= 1) acc += __shfl_down(acc, off);
        if (lane == 0) out[OUT_OFF + blk] = acc;
    } else {
        float dv = 0.0f, rg = 0.0f;
        #pragma unroll
        for (int r = 0; r < 10; ++r) {
            const int i = lane + r * 64;
            if (i < 640) dv += wsf[i];
        }
        if (lane < 4) rg = wsf[640 + lane];
        #pragma unroll
        for (int off = 32; off; off >>= 1) {
            dv += __shfl_down(dv, off);
            rg += __shfl_down(rg, off);
        }
        if (lane == 0)
            out[LOSS_OFF] = 0.1f * (rg * (1.0f / 1600.0f)) + 0.1f * (dv * (1.0f / 200.0f));
    }
}

extern "C" void kernel_launch(void* const* d_in, const int* in_sizes, int n_in,
                              void* d_out, int out_size, void* d_ws, size_t ws_size,
                              hipStream_t stream) {
    // setup_inputs() dict order: x, w0, pcm0, w1, pcm1, w2, pcm2, w3, pcm3, W_out
    const float* x    = (const float*)d_in[0];
    const float* w0   = (const float*)d_in[1];
    const float* pcm0 = (const float*)d_in[2];
    const float* w1   = (const float*)d_in[3];
    const float* pcm1 = (const float*)d_in[4];
    const float* w2   = (const float*)d_in[5];
    const float* pcm2 = (const float*)d_in[6];
    const float* w3   = (const float*)d_in[7];
    const float* pcm3 = (const float*)d_in[8];
    const float* Wout = (const float*)d_in[9];
    float* out = (float*)d_out;
    float* wsf = (float*)d_ws;

    prep_kernel<<<225, 256, 0, stream>>>(x, w0, w1, w2, w3, Wout, wsf);
    shapelet_kernel<<<1664, 256, 0, stream>>>(
        w0, w1, w2, w3, pcm0, pcm1, pcm2, pcm3, wsf);
    reduce_kernel<<<256, 256, 0, stream>>>(wsf, out);
    head_kernel<<<B * NCLS + 1, 64, 0, stream>>>(Wout, wsf, out);
}